// Round 1
// baseline (203.098 us; speedup 1.0000x reference)
//
#include <hip/hip_runtime.h>

// GWRouter: x = mean(wm_state [4,4096,2048] f32); sim[e] = -(proto[e]-x)^2;
// probs = softmax(sim); top-2; mask; EMA usage update; balance loss.
// Outputs flat f32: mask[0:16), probs[16:32), balance_loss[32],
// new_usage_ema[33:49), topk_idx[49:51) (written as float values).

#define NUM_EXPERTS 16
#define RED_BLOCKS 2048
#define RED_THREADS 256

__global__ __launch_bounds__(RED_THREADS)
void gw_reduce_partial(const float* __restrict__ x, double* __restrict__ partials, int n4) {
    __shared__ double sdata[RED_THREADS / 64];
    const int tid = blockIdx.x * blockDim.x + threadIdx.x;
    const int stride = gridDim.x * blockDim.x;
    const float4* __restrict__ x4 = (const float4*)x;

    double acc = 0.0;
    for (int i = tid; i < n4; i += stride) {
        float4 v = x4[i];
        acc += (double)v.x + (double)v.y + (double)v.z + (double)v.w;
    }
    // wave-64 reduction
    #pragma unroll
    for (int off = 32; off > 0; off >>= 1)
        acc += __shfl_down(acc, off, 64);

    const int lane = threadIdx.x & 63;
    const int wave = threadIdx.x >> 6;
    if (lane == 0) sdata[wave] = acc;
    __syncthreads();
    if (threadIdx.x == 0) {
        double s = 0.0;
        #pragma unroll
        for (int w = 0; w < RED_THREADS / 64; ++w) s += sdata[w];
        partials[blockIdx.x] = s;
    }
}

__global__ __launch_bounds__(64)
void gw_finalize(const double* __restrict__ partials,
                 const float* __restrict__ prototypes,
                 const float* __restrict__ usage_ema,
                 float* __restrict__ out,
                 long long n_total) {
    double acc = 0.0;
    for (int i = threadIdx.x; i < RED_BLOCKS; i += 64) acc += partials[i];
    #pragma unroll
    for (int off = 32; off > 0; off >>= 1)
        acc += __shfl_down(acc, off, 64);

    if (threadIdx.x == 0) {
        const float x = (float)(acc / (double)n_total);

        float sim[NUM_EXPERTS];
        float m = -1e30f;
        #pragma unroll
        for (int e = 0; e < NUM_EXPERTS; ++e) {
            float d = prototypes[e] - x;
            sim[e] = -d * d;
            m = fmaxf(m, sim[e]);
        }
        float probs[NUM_EXPERTS];
        float s = 0.0f;
        #pragma unroll
        for (int e = 0; e < NUM_EXPERTS; ++e) {
            probs[e] = expf(sim[e] - m);
            s += probs[e];
        }
        const float inv_s = 1.0f / s;
        #pragma unroll
        for (int e = 0; e < NUM_EXPERTS; ++e) probs[e] *= inv_s;

        // top-2, lowest-index tie-break (matches jax.lax.top_k)
        int i0 = 0;
        #pragma unroll
        for (int e = 1; e < NUM_EXPERTS; ++e)
            if (probs[e] > probs[i0]) i0 = e;
        int i1 = -1;
        #pragma unroll
        for (int e = 0; e < NUM_EXPERTS; ++e) {
            if (e == i0) continue;
            if (i1 < 0 || probs[e] > probs[i1]) i1 = e;
        }

        const float alpha = 1.0f / 1000.0f;
        const float target = 1.0f / (float)NUM_EXPERTS;
        float bal = 0.0f;
        #pragma unroll
        for (int e = 0; e < NUM_EXPERTS; ++e) {
            float mk = (e == i0 || e == i1) ? 1.0f : 0.0f;
            float ne = (1.0f - alpha) * usage_ema[e] + alpha * mk;
            out[e]      = mk;       // mask
            out[16 + e] = probs[e]; // probs
            out[33 + e] = ne;       // new_usage_ema
            float dlt = ne - target;
            bal += dlt * dlt;
        }
        out[32] = (bal / (float)NUM_EXPERTS) * 1e-3f; // balance_loss
        out[49] = (float)i0;                          // topk_idx
        out[50] = (float)i1;
    }
}

extern "C" void kernel_launch(void* const* d_in, const int* in_sizes, int n_in,
                              void* d_out, int out_size, void* d_ws, size_t ws_size,
                              hipStream_t stream) {
    const float* wm_state   = (const float*)d_in[0];
    const float* prototypes = (const float*)d_in[1];
    const float* usage_ema  = (const float*)d_in[2];
    float* out = (float*)d_out;

    const long long n_total = (long long)in_sizes[0];
    const int n4 = (int)(n_total / 4);

    double* partials = (double*)d_ws; // RED_BLOCKS doubles = 16 KiB

    gw_reduce_partial<<<RED_BLOCKS, RED_THREADS, 0, stream>>>(wm_state, partials, n4);
    gw_finalize<<<1, 64, 0, stream>>>(partials, prototypes, usage_ema, out, n_total);
}